// Round 17
// baseline (170.145 us; speedup 1.0000x reference)
//
#include <hip/hip_runtime.h>
#include <hip/hip_bf16.h>

typedef short short8 __attribute__((ext_vector_type(8)));
typedef float f32x4 __attribute__((ext_vector_type(4)));

#define S_IMG 16384
#define N_TXT 8192
#define DIM   512

#if __has_builtin(__builtin_amdgcn_exp2f)
#define FAST_EXP2(x) __builtin_amdgcn_exp2f(x)
#else
#define FAST_EXP2(x) exp2f(x)
#endif
#if __has_builtin(__builtin_amdgcn_logf)
#define FAST_LOG2(x) __builtin_amdgcn_logf(x)   // v_log_f32 = log2
#else
#define FAST_LOG2(x) log2f(x)
#endif
#if __has_builtin(__builtin_amdgcn_sched_barrier)
#define SCHED_FENCE() __builtin_amdgcn_sched_barrier(0)
#else
#define SCHED_FENCE()
#endif

// exact-ish softplus(x) = max(x,0) + ln2 * log2(1 + exp2(-|x|*log2e))
__device__ inline float softplus_f(float x) {
  float e = FAST_EXP2(-fabsf(x) * 1.44269504088896f);
  return fmaxf(x, 0.f) + 0.69314718055995f * FAST_LOG2(1.0f + e);
}

#define GLOAD16(g, l)                                                   \
  __builtin_amdgcn_global_load_lds(                                     \
      (const __attribute__((address_space(1))) void*)(g),               \
      (__attribute__((address_space(3))) void*)(l), 16, 0, 0)

__device__ inline unsigned short f2bf(float x) {
  unsigned u = __builtin_bit_cast(unsigned, x);
  unsigned r = (u + 0x7FFFu + ((u >> 16) & 1u)) >> 16;  // RNE
  return (unsigned short)r;
}

__device__ inline double wave_reduce_add_d(double v) {
#pragma unroll
  for (int m = 32; m; m >>= 1) v += __shfl_xor(v, m, 64);
  return v;
}

// ---------------- kernel 1: normalize txt rows -> ztxt f32 (d_out) + bf16 (ws) -------------
__global__ __launch_bounds__(256) void k_norm_txt(const float* __restrict__ txt,
                                                  float* __restrict__ ztxt_f32,
                                                  unsigned short* __restrict__ Bbf) {
  int row  = blockIdx.x * 4 + (threadIdx.x >> 6);
  int lane = threadIdx.x & 63;
  const float* src = txt + (size_t)row * DIM;
  float4 v0 = reinterpret_cast<const float4*>(src)[lane];
  float4 v1 = reinterpret_cast<const float4*>(src)[lane + 64];
  double ss = (double)v0.x * v0.x + (double)v0.y * v0.y + (double)v0.z * v0.z + (double)v0.w * v0.w
            + (double)v1.x * v1.x + (double)v1.y * v1.y + (double)v1.z * v1.z + (double)v1.w * v1.w;
  ss = wave_reduce_add_d(ss);
  float sc = (float)(1.0 / (sqrt(ss) + 1e-12));
  float o[8] = {v0.x * sc, v0.y * sc, v0.z * sc, v0.w * sc,
                v1.x * sc, v1.y * sc, v1.z * sc, v1.w * sc};
  float* dst = ztxt_f32 + (size_t)row * DIM;
#pragma unroll
  for (int j = 0; j < 4; ++j) dst[4 * lane + j] = o[j];
#pragma unroll
  for (int j = 0; j < 4; ++j) dst[256 + 4 * lane + j] = o[4 + j];
  ushort4 p0 = make_ushort4(f2bf(o[0]), f2bf(o[1]), f2bf(o[2]), f2bf(o[3]));
  ushort4 p1 = make_ushort4(f2bf(o[4]), f2bf(o[5]), f2bf(o[6]), f2bf(o[7]));
  reinterpret_cast<ushort4*>(Bbf + (size_t)row * DIM)[lane]       = p0;
  reinterpret_cast<ushort4*>(Bbf + (size_t)row * DIM + 256)[lane] = p1;
}

// ---------------- kernel 2: per-image tp-loss + segmented packed atomicMin ------------------
__global__ __launch_bounds__(256) void k_img_loss(const float* __restrict__ img,
                                                  const float* __restrict__ ztxt_f32,
                                                  const int* __restrict__ key_idx,
                                                  const float* __restrict__ tp,
                                                  const float* __restrict__ bp,
                                                  unsigned long long* __restrict__ seg,
                                                  float* __restrict__ invnorm) {
  int row  = blockIdx.x * 4 + (threadIdx.x >> 6);
  int lane = threadIdx.x & 63;
  const float* src = img + (size_t)row * DIM;
  float4 a0 = reinterpret_cast<const float4*>(src)[lane];
  float4 a1 = reinterpret_cast<const float4*>(src)[lane + 64];
  int key = key_idx[row];
  const float* zt = ztxt_f32 + (size_t)key * DIM;
  float z0[4], z1[4];
#pragma unroll
  for (int j = 0; j < 4; ++j) z0[j] = zt[4 * lane + j];
#pragma unroll
  for (int j = 0; j < 4; ++j) z1[j] = zt[256 + 4 * lane + j];
  double ss = (double)a0.x * a0.x + (double)a0.y * a0.y + (double)a0.z * a0.z + (double)a0.w * a0.w
            + (double)a1.x * a1.x + (double)a1.y * a1.y + (double)a1.z * a1.z + (double)a1.w * a1.w;
  double dp = (double)a0.x * z0[0] + (double)a0.y * z0[1] + (double)a0.z * z0[2] + (double)a0.w * z0[3]
            + (double)a1.x * z1[0] + (double)a1.y * z1[1] + (double)a1.z * z1[2] + (double)a1.w * z1[3];
  ss = wave_reduce_add_d(ss);
  dp = wave_reduce_add_d(dp);
  if (lane == 0) {
    double inv = 1.0 / (sqrt(ss) + 1e-12);
    invnorm[row] = (float)inv;
    float t = expf(tp[0]);
    float logit = (float)(dp * inv) * t + bp[0];
    float loss = log1pf(expf(-logit));  // exact libm here (argmin-critical)
    unsigned long long pk =
        ((unsigned long long)__builtin_bit_cast(unsigned, loss) << 32) | (unsigned)row;
    atomicMin(seg + key, pk);
  }
}

// ---------------- kernel 3: select winner per key, gather + normalize ----------------------
__global__ __launch_bounds__(256) void k_select(const float* __restrict__ img,
                                                const unsigned long long* __restrict__ seg,
                                                const float* __restrict__ invnorm,
                                                float* __restrict__ zsel_f32,
                                                float* __restrict__ idx_out,
                                                unsigned short* __restrict__ Abf) {
  int k    = blockIdx.x * 4 + (threadIdx.x >> 6);
  int lane = threadIdx.x & 63;
  unsigned long long pk = seg[k];
  float* dst = zsel_f32 + (size_t)k * DIM;
  float o[8];
  if (pk == 0xFFFFFFFFFFFFFFFFull) {
#pragma unroll
    for (int j = 0; j < 8; ++j) o[j] = 0.0f;
    if (lane == 0) idx_out[k] = -1.0f;
  } else {
    int sel = (int)(pk & 0xFFFFFFFFull);
    float invf = invnorm[sel];
    const float* src = img + (size_t)sel * DIM;
    float4 v0 = reinterpret_cast<const float4*>(src)[lane];
    float4 v1 = reinterpret_cast<const float4*>(src)[lane + 64];
    o[0] = v0.x * invf; o[1] = v0.y * invf; o[2] = v0.z * invf; o[3] = v0.w * invf;
    o[4] = v1.x * invf; o[5] = v1.y * invf; o[6] = v1.z * invf; o[7] = v1.w * invf;
    if (lane == 0) idx_out[k] = (float)sel;
  }
#pragma unroll
  for (int j = 0; j < 4; ++j) dst[4 * lane + j] = o[j];
#pragma unroll
  for (int j = 0; j < 4; ++j) dst[256 + 4 * lane + j] = o[4 + j];
  ushort4 p0 = make_ushort4(f2bf(o[0]), f2bf(o[1]), f2bf(o[2]), f2bf(o[3]));
  ushort4 p1 = make_ushort4(f2bf(o[4]), f2bf(o[5]), f2bf(o[6]), f2bf(o[7]));
  reinterpret_cast<ushort4*>(Abf + (size_t)k * DIM)[lane]       = p0;
  reinterpret_cast<ushort4*>(Abf + (size_t)k * DIM + 256)[lane] = p1;
}

// ---------------- kernel 4: Zsel @ Ztxt^T * t + b  -> logits, fused loss -------------------
// R14 = R12 with BK=32 + THREE buffers -> depth-2 counted prefetch (same 256x256,
// 8 waves, minimal-read frags: 12 ds_read per 32 MFMA per wave per tile).
//   iter t: STAGE((t+2)%3) [4 loads/wave] ; vmcnt(8) ; barrier ;
//           read B once (4) + A once (8) ; 32 MFMA ; barrier
// Loads get ~2 tiles (~5000 cyc) to land (C-store stream evicts A/B from L2 ->
// staging is L3-latency class; depth-1 was marginal). Buffer rewrite race-free:
// buf (u-1)%3 consumed at iter u-1 (closing barrier) is rewritten by stage at iter u.
// Epilogue v2 (LDS-staged, 128B-line-aligned, no RFO) + pre-swizzled staging kept.
#define BM 256
#define BN 256
#define BK 32
#define NSTEP (DIM / BK)   // 16

__global__ __launch_bounds__(512, 2) void k_gemm(const unsigned short* __restrict__ A,
                                                 const unsigned short* __restrict__ B,
                                                 float* __restrict__ Cout,
                                                 const float* __restrict__ tp,
                                                 const float* __restrict__ bp,
                                                 float* __restrict__ part) {
  // [3 buf][0=A(256x32), 1=B(256x32)] -> 96 KiB
  __shared__ __align__(16) unsigned short lds[3][2][256 * 32];
  int tid = threadIdx.x, lane = tid & 63, w = tid >> 6;         // 8 waves
  int wm = w >> 2, wn = w & 3;

  int bid = blockIdx.x;
  int xcd = bid & 7, rr = bid >> 3;
  int bm = ((xcd << 2) + (rr & 3)) * BM;   // 32 m-tiles
  int bn = (rr >> 2) * BN;                 // 32 n-tiles

  f32x4 acc[8][4] = {};
  int fr   = lane & 15;
  int phys = ((lane >> 4) ^ ((fr >> 1) & 3)) * 8;   // swizzled 16B slot, elements
  int brow = wn * 64;                               // B rows for this wave's n-range

  // staging: 16-row chunks; wave w takes chunks w (rows w*16) and w+8 (rows 128+w*16)
  int srow = lane >> 2;                             // 0..15
  int scol = ((lane & 3) ^ ((lane >> 3) & 3)) * 8;  // inverse swizzle source col
  const unsigned short* gA = A + (size_t)(bm + w * 16 + srow) * DIM + scol;
  const unsigned short* gB = B + (size_t)(bn + w * 16 + srow) * DIM + scol;

#define STAGE(buf, kk)                                                  \
  do {                                                                  \
    GLOAD16(gA + (kk),             &lds[buf][0][(w * 16) * BK]);        \
    GLOAD16(gA + (kk) + 128 * DIM, &lds[buf][0][((w + 8) * 16) * BK]);  \
    GLOAD16(gB + (kk),             &lds[buf][1][(w * 16) * BK]);        \
    GLOAD16(gB + (kk) + 128 * DIM, &lds[buf][1][((w + 8) * 16) * BK]);  \
  } while (0)

  STAGE(0, 0);
  STAGE(1, BK);
  for (int t = 0; t < NSTEP; ++t) {
    int buf = t % 3;
    if (t + 2 < NSTEP) {
      STAGE((t + 2) % 3, (t + 2) * BK);
      asm volatile("s_waitcnt vmcnt(8)" ::: "memory");   // stage(t) done; 8 in flight
    } else if (t + 1 < NSTEP) {
      asm volatile("s_waitcnt vmcnt(4)" ::: "memory");
    } else {
      asm volatile("s_waitcnt vmcnt(0)" ::: "memory");
    }
    __builtin_amdgcn_s_barrier();
    SCHED_FENCE();
    const unsigned short* LA = lds[buf][0] + wm * 128 * BK;
    const unsigned short* LB = lds[buf][1];
    short8 bfr[4];
#pragma unroll
    for (int n = 0; n < 4; ++n)
      bfr[n] = *reinterpret_cast<const short8*>(&LB[(brow + n * 16 + fr) * BK + phys]);
    short8 afr[8];
#pragma unroll
    for (int m = 0; m < 8; ++m)
      afr[m] = *reinterpret_cast<const short8*>(&LA[(m * 16 + fr) * BK + phys]);
    __builtin_amdgcn_s_setprio(1);
#pragma unroll
    for (int m = 0; m < 8; ++m)
#pragma unroll
      for (int n = 0; n < 4; ++n)   // swapped operands -> C row = lane&15, col = (lane>>4)*4+r
        acc[m][n] = __builtin_amdgcn_mfma_f32_16x16x32_bf16(bfr[n], afr[m], acc[m][n], 0, 0, 0);
    __builtin_amdgcn_s_setprio(0);
    __builtin_amdgcn_s_barrier();   // reads of buf done before rewrite at t+1's stage
  }

  // ---- epilogue v2: fused loss + LDS-staged, 128B-line-aligned C writes (R11/R12) ----
  float tt = expf(tp[0]), bb = bp[0];
  const float L2E = 1.44269504088896f;
  float local = 0.f;
  int orow = lane & 15;
  int oc4  = (lane >> 4) * 4;
  float* clds = reinterpret_cast<float*>(&lds[0][0][0]) + 1;  // [64][260] +1 shim (aliases bufs)
  int lr_r = tid >> 3, m8 = tid & 7;
#pragma unroll
  for (int p = 0; p < 4; ++p) {
    __syncthreads();
    if (wm == (p >> 1)) {
      int mbase = (p & 1) * 4;
#pragma unroll
      for (int mm = 0; mm < 4; ++mm) {
        int m = mbase + mm;
        int rowbase = bm + wm * 128 + m * 16;
#pragma unroll
        for (int n = 0; n < 4; ++n) {
          int colbase = bn + wn * 64 + n * 16;
          int lc = wn * 64 + n * 16 + oc4;
          int lr = mm * 16 + orow;
          float ov[4];
          if (rowbase == colbase) {
#pragma unroll
            for (int r2 = 0; r2 < 4; ++r2) {
              float logit = acc[m][n][r2] * tt + bb;
              ov[r2] = logit;
              float x = (orow == oc4 + r2) ? -logit : logit;
              local += softplus_f(x);
            }
          } else {
#pragma unroll
            for (int r2 = 0; r2 < 4; ++r2) {
              float logit = acc[m][n][r2] * tt + bb;
              ov[r2] = logit;
              float u = FAST_EXP2(logit * L2E);
              local += fmaf(-0.5f * u, u, u);
            }
          }
#pragma unroll
          for (int r2 = 0; r2 < 4; ++r2) clds[lr * 260 + lc + r2] = ov[r2];
        }
      }
    }
    __syncthreads();
    {
      float* gp = Cout + (size_t)(bm + p * 64 + lr_r) * N_TXT + bn;
      const float* lp = &clds[lr_r * 260];
#pragma unroll
      for (int K = 0; K < 7; ++K) {
        int c = 31 + 32 * K + 4 * m8;
        *reinterpret_cast<f32x4*>(gp + c) = *reinterpret_cast<const f32x4*>(lp + c);
      }
      if (m8 < 7) {
        int c = 3 + 4 * m8;
        *reinterpret_cast<f32x4*>(gp + c) = *reinterpret_cast<const f32x4*>(lp + c);
      }
      if (m8 < 3) gp[m8] = lp[m8];
      else if (m8 == 3) gp[255] = lp[255];
    }
  }
#pragma unroll
  for (int m = 32; m; m >>= 1) local += __shfl_xor(local, m, 64);
  __shared__ float wsum[8];
  if (lane == 0) wsum[w] = local;
  __syncthreads();
  if (tid == 0) {
    float sum = 0.f;
#pragma unroll
    for (int i = 0; i < 8; ++i) sum += wsum[i];
    part[bid] = sum;
  }
}

// ---------------- kernel 5: reduce partials, finalize loss ---------------------------------
#define NPART 1024
__global__ __launch_bounds__(256) void k_final(const float* __restrict__ part,
                                               float* __restrict__ out0) {
  double s = 0.0;
  for (int i = threadIdx.x; i < NPART; i += 256) s += (double)part[i];
  s = wave_reduce_add_d(s);
  __shared__ double ws[4];
  if ((threadIdx.x & 63) == 0) ws[threadIdx.x >> 6] = s;
  __syncthreads();
  if (threadIdx.x == 0)
    out0[0] = (float)((ws[0] + ws[1] + ws[2] + ws[3]) / (double)N_TXT);
}

extern "C" void kernel_launch(void* const* d_in, const int* in_sizes, int n_in,
                              void* d_out, int out_size, void* d_ws, size_t ws_size,
                              hipStream_t stream) {
  const float* img = (const float*)d_in[0];
  const float* txt = (const float*)d_in[1];
  const int* key   = (const int*)d_in[2];
  const float* tp  = (const float*)d_in[3];
  const float* bp  = (const float*)d_in[4];

  float* out        = (float*)d_out;
  float* out_loss   = out;                                   // [1]
  float* out_zsel   = out + 1;                               // [8192*512]
  float* out_ztxt   = out_zsel + (size_t)N_TXT * DIM;        // [8192*512]
  float* out_logits = out_ztxt + (size_t)N_TXT * DIM;        // [8192*8192]
  float* out_idx    = out_logits + (size_t)N_TXT * N_TXT;    // [8192]

  char* w = (char*)d_ws;
  unsigned long long* seg = (unsigned long long*)w;          // 64 KiB
  float* invnorm   = (float*)(w + 65536);                    // 64 KiB
  float* part      = (float*)(w + 131072);                   // 16 KiB
  unsigned short* Abf = (unsigned short*)(w + 131072 + 16384);      // 8 MiB, 16B aligned
  unsigned short* Bbf = Abf + (size_t)N_TXT * DIM;                  // 8 MiB
  size_t need = 131072 + 16384 + 2ull * N_TXT * DIM * sizeof(unsigned short);
  if (ws_size < need) return;

  (void)hipMemsetAsync(seg, 0xFF, (size_t)N_TXT * sizeof(unsigned long long), stream);

  k_norm_txt<<<N_TXT / 4, 256, 0, stream>>>(txt, out_ztxt, Bbf);
  k_img_loss<<<S_IMG / 4, 256, 0, stream>>>(img, out_ztxt, key, tp, bp, seg, invnorm);
  k_select<<<N_TXT / 4, 256, 0, stream>>>(img, seg, invnorm, out_zsel, out_idx, Abf);
  k_gemm<<<N_TXT / BM * (N_TXT / BN), 512, 0, stream>>>(Abf, Bbf, out_logits, tp, bp, part);
  k_final<<<1, 256, 0, stream>>>(part, out_loss);
}

// Round 18
// 155.669 us; speedup vs baseline: 1.0930x; 1.0930x over previous
//
#include <hip/hip_runtime.h>
#include <hip/hip_bf16.h>

typedef short short8 __attribute__((ext_vector_type(8)));
typedef float f32x4 __attribute__((ext_vector_type(4)));

#define S_IMG 16384
#define N_TXT 8192
#define DIM   512

#if __has_builtin(__builtin_amdgcn_exp2f)
#define FAST_EXP2(x) __builtin_amdgcn_exp2f(x)
#else
#define FAST_EXP2(x) exp2f(x)
#endif
#if __has_builtin(__builtin_amdgcn_logf)
#define FAST_LOG2(x) __builtin_amdgcn_logf(x)   // v_log_f32 = log2
#else
#define FAST_LOG2(x) log2f(x)
#endif
#if __has_builtin(__builtin_amdgcn_sched_barrier)
#define SCHED_FENCE() __builtin_amdgcn_sched_barrier(0)
#else
#define SCHED_FENCE()
#endif

// exact-ish softplus(x) = max(x,0) + ln2 * log2(1 + exp2(-|x|*log2e))
__device__ inline float softplus_f(float x) {
  float e = FAST_EXP2(-fabsf(x) * 1.44269504088896f);
  return fmaxf(x, 0.f) + 0.69314718055995f * FAST_LOG2(1.0f + e);
}

#define GLOAD16(g, l)                                                   \
  __builtin_amdgcn_global_load_lds(                                     \
      (const __attribute__((address_space(1))) void*)(g),               \
      (__attribute__((address_space(3))) void*)(l), 16, 0, 0)

__device__ inline unsigned short f2bf(float x) {
  unsigned u = __builtin_bit_cast(unsigned, x);
  unsigned r = (u + 0x7FFFu + ((u >> 16) & 1u)) >> 16;  // RNE
  return (unsigned short)r;
}

__device__ inline double wave_reduce_add_d(double v) {
#pragma unroll
  for (int m = 32; m; m >>= 1) v += __shfl_xor(v, m, 64);
  return v;
}

// ---------------- kernel 1: normalize txt rows -> ztxt f32 (d_out) + bf16 (ws) -------------
__global__ __launch_bounds__(256) void k_norm_txt(const float* __restrict__ txt,
                                                  float* __restrict__ ztxt_f32,
                                                  unsigned short* __restrict__ Bbf) {
  int row  = blockIdx.x * 4 + (threadIdx.x >> 6);
  int lane = threadIdx.x & 63;
  const float* src = txt + (size_t)row * DIM;
  float4 v0 = reinterpret_cast<const float4*>(src)[lane];
  float4 v1 = reinterpret_cast<const float4*>(src)[lane + 64];
  double ss = (double)v0.x * v0.x + (double)v0.y * v0.y + (double)v0.z * v0.z + (double)v0.w * v0.w
            + (double)v1.x * v1.x + (double)v1.y * v1.y + (double)v1.z * v1.z + (double)v1.w * v1.w;
  ss = wave_reduce_add_d(ss);
  float sc = (float)(1.0 / (sqrt(ss) + 1e-12));
  float o[8] = {v0.x * sc, v0.y * sc, v0.z * sc, v0.w * sc,
                v1.x * sc, v1.y * sc, v1.z * sc, v1.w * sc};
  float* dst = ztxt_f32 + (size_t)row * DIM;
#pragma unroll
  for (int j = 0; j < 4; ++j) dst[4 * lane + j] = o[j];
#pragma unroll
  for (int j = 0; j < 4; ++j) dst[256 + 4 * lane + j] = o[4 + j];
  ushort4 p0 = make_ushort4(f2bf(o[0]), f2bf(o[1]), f2bf(o[2]), f2bf(o[3]));
  ushort4 p1 = make_ushort4(f2bf(o[4]), f2bf(o[5]), f2bf(o[6]), f2bf(o[7]));
  reinterpret_cast<ushort4*>(Bbf + (size_t)row * DIM)[lane]       = p0;
  reinterpret_cast<ushort4*>(Bbf + (size_t)row * DIM + 256)[lane] = p1;
}

// ---------------- kernel 2: per-image tp-loss + segmented packed atomicMin ------------------
__global__ __launch_bounds__(256) void k_img_loss(const float* __restrict__ img,
                                                  const float* __restrict__ ztxt_f32,
                                                  const int* __restrict__ key_idx,
                                                  const float* __restrict__ tp,
                                                  const float* __restrict__ bp,
                                                  unsigned long long* __restrict__ seg,
                                                  float* __restrict__ invnorm) {
  int row  = blockIdx.x * 4 + (threadIdx.x >> 6);
  int lane = threadIdx.x & 63;
  const float* src = img + (size_t)row * DIM;
  float4 a0 = reinterpret_cast<const float4*>(src)[lane];
  float4 a1 = reinterpret_cast<const float4*>(src)[lane + 64];
  int key = key_idx[row];
  const float* zt = ztxt_f32 + (size_t)key * DIM;
  float z0[4], z1[4];
#pragma unroll
  for (int j = 0; j < 4; ++j) z0[j] = zt[4 * lane + j];
#pragma unroll
  for (int j = 0; j < 4; ++j) z1[j] = zt[256 + 4 * lane + j];
  double ss = (double)a0.x * a0.x + (double)a0.y * a0.y + (double)a0.z * a0.z + (double)a0.w * a0.w
            + (double)a1.x * a1.x + (double)a1.y * a1.y + (double)a1.z * a1.z + (double)a1.w * a1.w;
  double dp = (double)a0.x * z0[0] + (double)a0.y * z0[1] + (double)a0.z * z0[2] + (double)a0.w * z0[3]
            + (double)a1.x * z1[0] + (double)a1.y * z1[1] + (double)a1.z * z1[2] + (double)a1.w * z1[3];
  ss = wave_reduce_add_d(ss);
  dp = wave_reduce_add_d(dp);
  if (lane == 0) {
    double inv = 1.0 / (sqrt(ss) + 1e-12);
    invnorm[row] = (float)inv;
    float t = expf(tp[0]);
    float logit = (float)(dp * inv) * t + bp[0];
    float loss = log1pf(expf(-logit));  // exact libm here (argmin-critical)
    unsigned long long pk =
        ((unsigned long long)__builtin_bit_cast(unsigned, loss) << 32) | (unsigned)row;
    atomicMin(seg + key, pk);
  }
}

// ---------------- kernel 3: select winner per key, gather + normalize ----------------------
__global__ __launch_bounds__(256) void k_select(const float* __restrict__ img,
                                                const unsigned long long* __restrict__ seg,
                                                const float* __restrict__ invnorm,
                                                float* __restrict__ zsel_f32,
                                                float* __restrict__ idx_out,
                                                unsigned short* __restrict__ Abf) {
  int k    = blockIdx.x * 4 + (threadIdx.x >> 6);
  int lane = threadIdx.x & 63;
  unsigned long long pk = seg[k];
  float* dst = zsel_f32 + (size_t)k * DIM;
  float o[8];
  if (pk == 0xFFFFFFFFFFFFFFFFull) {
#pragma unroll
    for (int j = 0; j < 8; ++j) o[j] = 0.0f;
    if (lane == 0) idx_out[k] = -1.0f;
  } else {
    int sel = (int)(pk & 0xFFFFFFFFull);
    float invf = invnorm[sel];
    const float* src = img + (size_t)sel * DIM;
    float4 v0 = reinterpret_cast<const float4*>(src)[lane];
    float4 v1 = reinterpret_cast<const float4*>(src)[lane + 64];
    o[0] = v0.x * invf; o[1] = v0.y * invf; o[2] = v0.z * invf; o[3] = v0.w * invf;
    o[4] = v1.x * invf; o[5] = v1.y * invf; o[6] = v1.z * invf; o[7] = v1.w * invf;
    if (lane == 0) idx_out[k] = (float)sel;
  }
#pragma unroll
  for (int j = 0; j < 4; ++j) dst[4 * lane + j] = o[j];
#pragma unroll
  for (int j = 0; j < 4; ++j) dst[256 + 4 * lane + j] = o[4 + j];
  ushort4 p0 = make_ushort4(f2bf(o[0]), f2bf(o[1]), f2bf(o[2]), f2bf(o[3]));
  ushort4 p1 = make_ushort4(f2bf(o[4]), f2bf(o[5]), f2bf(o[6]), f2bf(o[7]));
  reinterpret_cast<ushort4*>(Abf + (size_t)k * DIM)[lane]       = p0;
  reinterpret_cast<ushort4*>(Abf + (size_t)k * DIM + 256)[lane] = p1;
}

// ---------------- kernel 4: Zsel @ Ztxt^T * t + b  -> logits, fused loss -------------------
// R18: 256x256, 8 waves, BK=32, THREE buffers -> ONE barrier per K-tile.
// iter t: STAGE((t+1)%3) [4 loads/wave] ; vmcnt(4) [own stage(t) landed] ; barrier ;
//         12 frag reads ; 32 MFMA ; (no closing barrier)
// Safety with 3 bufs + 1 barrier: stage at iter t writes buf (t+1)%3; laggards (pre-
// barrier_t) read buf (t-1)%3 (distinct mod 3); readers of buf t start post-barrier_t,
// and every wave's vmcnt(4) precedes its barrier_t -> all waves' stage(t) complete.
// Buf (t-1)%3 is rewritten by stage(t+2) at iter t+1 (after barrier_t), and a wave's
// iter t-1 ds_reads complete before it can issue the MFMAs that precede barrier_t.
// Waves may drift one tile apart -> one wave's ds_reads overlap another's MFMAs
// (lockstep 2-barrier schedule forbids this; suspected residual stall per m233).
// Epilogue v2 (LDS-staged, 128B-line-aligned, no RFO) + pre-swizzled staging kept.
#define BM 256
#define BN 256
#define BK 32
#define NSTEP (DIM / BK)   // 16

__global__ __launch_bounds__(512, 2) void k_gemm(const unsigned short* __restrict__ A,
                                                 const unsigned short* __restrict__ B,
                                                 float* __restrict__ Cout,
                                                 const float* __restrict__ tp,
                                                 const float* __restrict__ bp,
                                                 float* __restrict__ part) {
  // [3 buf][0=A(256x32), 1=B(256x32)] -> 96 KiB
  __shared__ __align__(16) unsigned short lds[3][2][256 * 32];
  int tid = threadIdx.x, lane = tid & 63, w = tid >> 6;         // 8 waves
  int wm = w >> 2, wn = w & 3;

  int bid = blockIdx.x;
  int xcd = bid & 7, rr = bid >> 3;
  int bm = ((xcd << 2) + (rr & 3)) * BM;   // 32 m-tiles
  int bn = (rr >> 2) * BN;                 // 32 n-tiles

  f32x4 acc[8][4] = {};
  int fr   = lane & 15;
  int phys = ((lane >> 4) ^ ((fr >> 1) & 3)) * 8;   // swizzled 16B slot, elements
  int brow = wn * 64;                               // B rows for this wave's n-range

  // staging: 16-row chunks; wave w takes chunks w (rows w*16) and w+8 (rows 128+w*16)
  int srow = lane >> 2;                             // 0..15
  int scol = ((lane & 3) ^ ((lane >> 3) & 3)) * 8;  // inverse swizzle source col
  const unsigned short* gA = A + (size_t)(bm + w * 16 + srow) * DIM + scol;
  const unsigned short* gB = B + (size_t)(bn + w * 16 + srow) * DIM + scol;

#define STAGE(buf, kk)                                                  \
  do {                                                                  \
    GLOAD16(gA + (kk),             &lds[buf][0][(w * 16) * BK]);        \
    GLOAD16(gA + (kk) + 128 * DIM, &lds[buf][0][((w + 8) * 16) * BK]);  \
    GLOAD16(gB + (kk),             &lds[buf][1][(w * 16) * BK]);        \
    GLOAD16(gB + (kk) + 128 * DIM, &lds[buf][1][((w + 8) * 16) * BK]);  \
  } while (0)

  STAGE(0, 0);
  for (int t = 0; t < NSTEP; ++t) {
    int buf = t % 3;
    if (t + 1 < NSTEP) {
      STAGE((t + 1) % 3, (t + 1) * BK);
      asm volatile("s_waitcnt vmcnt(4)" ::: "memory");   // own stage(t) landed; t+1 in flight
    } else {
      asm volatile("s_waitcnt vmcnt(0)" ::: "memory");
    }
    __builtin_amdgcn_s_barrier();   // all waves' stage(t) landed (each vmcnt precedes this)
    SCHED_FENCE();
    const unsigned short* LA = lds[buf][0] + wm * 128 * BK;
    const unsigned short* LB = lds[buf][1];
    short8 bfr[4];
#pragma unroll
    for (int n = 0; n < 4; ++n)
      bfr[n] = *reinterpret_cast<const short8*>(&LB[(brow + n * 16 + fr) * BK + phys]);
    short8 afr[8];
#pragma unroll
    for (int m = 0; m < 8; ++m)
      afr[m] = *reinterpret_cast<const short8*>(&LA[(m * 16 + fr) * BK + phys]);
    __builtin_amdgcn_s_setprio(1);
#pragma unroll
    for (int m = 0; m < 8; ++m)
#pragma unroll
      for (int n = 0; n < 4; ++n)   // swapped operands -> C row = lane&15, col = (lane>>4)*4+r
        acc[m][n] = __builtin_amdgcn_mfma_f32_16x16x32_bf16(bfr[n], afr[m], acc[m][n], 0, 0, 0);
    __builtin_amdgcn_s_setprio(0);
    // no closing barrier: 3 buffers make the rewrite safe; waves may drift one tile
  }

  // ---- epilogue v2: fused loss + LDS-staged, 128B-line-aligned C writes (R11/R12) ----
  float tt = expf(tp[0]), bb = bp[0];
  const float L2E = 1.44269504088896f;
  float local = 0.f;
  int orow = lane & 15;
  int oc4  = (lane >> 4) * 4;
  float* clds = reinterpret_cast<float*>(&lds[0][0][0]) + 1;  // [64][260] +1 shim (aliases bufs)
  int lr_r = tid >> 3, m8 = tid & 7;
#pragma unroll
  for (int p = 0; p < 4; ++p) {
    __syncthreads();   // orders clds reuse vs K-loop reads (p=0) and prior readback (p>0)
    if (wm == (p >> 1)) {
      int mbase = (p & 1) * 4;
#pragma unroll
      for (int mm = 0; mm < 4; ++mm) {
        int m = mbase + mm;
        int rowbase = bm + wm * 128 + m * 16;
#pragma unroll
        for (int n = 0; n < 4; ++n) {
          int colbase = bn + wn * 64 + n * 16;
          int lc = wn * 64 + n * 16 + oc4;
          int lr = mm * 16 + orow;
          float ov[4];
          if (rowbase == colbase) {
#pragma unroll
            for (int r2 = 0; r2 < 4; ++r2) {
              float logit = acc[m][n][r2] * tt + bb;
              ov[r2] = logit;
              float x = (orow == oc4 + r2) ? -logit : logit;
              local += softplus_f(x);
            }
          } else {
#pragma unroll
            for (int r2 = 0; r2 < 4; ++r2) {
              float logit = acc[m][n][r2] * tt + bb;
              ov[r2] = logit;
              float u = FAST_EXP2(logit * L2E);
              local += fmaf(-0.5f * u, u, u);
            }
          }
#pragma unroll
          for (int r2 = 0; r2 < 4; ++r2) clds[lr * 260 + lc + r2] = ov[r2];
        }
      }
    }
    __syncthreads();
    {
      float* gp = Cout + (size_t)(bm + p * 64 + lr_r) * N_TXT + bn;
      const float* lp = &clds[lr_r * 260];
#pragma unroll
      for (int K = 0; K < 7; ++K) {
        int c = 31 + 32 * K + 4 * m8;
        *reinterpret_cast<f32x4*>(gp + c) = *reinterpret_cast<const f32x4*>(lp + c);
      }
      if (m8 < 7) {
        int c = 3 + 4 * m8;
        *reinterpret_cast<f32x4*>(gp + c) = *reinterpret_cast<const f32x4*>(lp + c);
      }
      if (m8 < 3) gp[m8] = lp[m8];
      else if (m8 == 3) gp[255] = lp[255];
    }
  }
#pragma unroll
  for (int m = 32; m; m >>= 1) local += __shfl_xor(local, m, 64);
  __shared__ float wsum[8];
  if (lane == 0) wsum[w] = local;
  __syncthreads();
  if (tid == 0) {
    float sum = 0.f;
#pragma unroll
    for (int i = 0; i < 8; ++i) sum += wsum[i];
    part[bid] = sum;
  }
}

// ---------------- kernel 5: reduce partials, finalize loss ---------------------------------
#define NPART 1024
__global__ __launch_bounds__(256) void k_final(const float* __restrict__ part,
                                               float* __restrict__ out0) {
  double s = 0.0;
  for (int i = threadIdx.x; i < NPART; i += 256) s += (double)part[i];
  s = wave_reduce_add_d(s);
  __shared__ double ws[4];
  if ((threadIdx.x & 63) == 0) ws[threadIdx.x >> 6] = s;
  __syncthreads();
  if (threadIdx.x == 0)
    out0[0] = (float)((ws[0] + ws[1] + ws[2] + ws[3]) / (double)N_TXT);
}

extern "C" void kernel_launch(void* const* d_in, const int* in_sizes, int n_in,
                              void* d_out, int out_size, void* d_ws, size_t ws_size,
                              hipStream_t stream) {
  const float* img = (const float*)d_in[0];
  const float* txt = (const float*)d_in[1];
  const int* key   = (const int*)d_in[2];
  const float* tp  = (const float*)d_in[3];
  const float* bp  = (const float*)d_in[4];

  float* out        = (float*)d_out;
  float* out_loss   = out;                                   // [1]
  float* out_zsel   = out + 1;                               // [8192*512]
  float* out_ztxt   = out_zsel + (size_t)N_TXT * DIM;        // [8192*512]
  float* out_logits = out_ztxt + (size_t)N_TXT * DIM;        // [8192*8192]
  float* out_idx    = out_logits + (size_t)N_TXT * N_TXT;    // [8192]

  char* w = (char*)d_ws;
  unsigned long long* seg = (unsigned long long*)w;          // 64 KiB
  float* invnorm   = (float*)(w + 65536);                    // 64 KiB
  float* part      = (float*)(w + 131072);                   // 16 KiB
  unsigned short* Abf = (unsigned short*)(w + 131072 + 16384);      // 8 MiB, 16B aligned
  unsigned short* Bbf = Abf + (size_t)N_TXT * DIM;                  // 8 MiB
  size_t need = 131072 + 16384 + 2ull * N_TXT * DIM * sizeof(unsigned short);
  if (ws_size < need) return;

  (void)hipMemsetAsync(seg, 0xFF, (size_t)N_TXT * sizeof(unsigned long long), stream);

  k_norm_txt<<<N_TXT / 4, 256, 0, stream>>>(txt, out_ztxt, Bbf);
  k_img_loss<<<S_IMG / 4, 256, 0, stream>>>(img, out_ztxt, key, tp, bp, seg, invnorm);
  k_select<<<N_TXT / 4, 256, 0, stream>>>(img, seg, invnorm, out_zsel, out_idx, Abf);
  k_gemm<<<N_TXT / BM * (N_TXT / BN), 512, 0, stream>>>(Abf, Bbf, out_logits, tp, bp, part);
  k_final<<<1, 256, 0, stream>>>(part, out_loss);
}